// Round 5
// baseline (51923.779 us; speedup 1.0000x reference)
//
#include <hip/hip_runtime.h>
#include <hip/hip_bf16.h>
#include <cstdint>

#define T_STEPS 8192
#define NWG2 64

typedef unsigned long long ull;

__device__ __forceinline__ float sigmoidf_(float v) { return 1.f / (1.f + __expf(-v)); }

__device__ __forceinline__ ull packpair(float v, unsigned tag) {
  return ((ull)__float_as_uint(v) << 32) | (ull)tag;
}

// ---------- grouped linear (8 groups of 64x64) + relu, one block per row ----------
__global__ __launch_bounds__(256) void k_grouped_relu(const float* __restrict__ in,
                                                      const float* __restrict__ W,
                                                      float* __restrict__ out) {
  __shared__ float es[512];
  const int t = blockIdx.x;
  const int tid = threadIdx.x;
  const float* inr = in + (size_t)t * 512;
  ((float2*)es)[tid] = ((const float2*)inr)[tid];
  __syncthreads();
#pragma unroll
  for (int rep = 0; rep < 2; ++rep) {
    int jj = tid + rep * 256;
    int g = jj >> 6, o = jj & 63;
    const float* wp = W + (g << 12) + o;   // W[g][i][o], stride 64 over i
    const float* ep = es + (g << 6);
    float acc = 0.f;
#pragma unroll 8
    for (int i = 0; i < 64; ++i) acc = fmaf(ep[i], wp[i << 6], acc);
    out[(size_t)t * 512 + jj] = fmaxf(acc, 0.f);
  }
}

// ---------- C[M,N] = A[M,512] * B[N,512]^T + bias[N] (+ add[M,N]) ----------
__global__ __launch_bounds__(256) void k_gemm_rr(const float* __restrict__ A,
                                                 const float* __restrict__ B,
                                                 const float* __restrict__ bias,
                                                 const float* __restrict__ add,
                                                 float* __restrict__ C, int N) {
  __shared__ float As[64][68];  // [k][m]
  __shared__ float Bs[64][68];  // [k][n]
  const int bm = blockIdx.x << 6, bn = blockIdx.y << 6;
  const int tid = threadIdx.x;
  const int tx = tid & 15, ty = tid >> 4;
  float acc[4][4] = {};
  for (int k0 = 0; k0 < 512; k0 += 64) {
#pragma unroll
    for (int u = 0; u < 4; ++u) {
      int f4 = (u << 8) + tid;          // 0..1023
      int m = f4 >> 4;                  // 0..63
      int kq = (f4 & 15) << 2;          // 0..60
      float4 av = *(const float4*)(A + (size_t)(bm + m) * 512 + k0 + kq);
      As[kq + 0][m] = av.x; As[kq + 1][m] = av.y; As[kq + 2][m] = av.z; As[kq + 3][m] = av.w;
      float4 bv = *(const float4*)(B + (size_t)(bn + m) * 512 + k0 + kq);
      Bs[kq + 0][m] = bv.x; Bs[kq + 1][m] = bv.y; Bs[kq + 2][m] = bv.z; Bs[kq + 3][m] = bv.w;
    }
    __syncthreads();
#pragma unroll
    for (int k = 0; k < 64; ++k) {
      float4 a4 = *(const float4*)(&As[k][ty << 2]);
      float4 b4 = *(const float4*)(&Bs[k][tx << 2]);
      float ar[4] = {a4.x, a4.y, a4.z, a4.w};
      float br[4] = {b4.x, b4.y, b4.z, b4.w};
#pragma unroll
      for (int i = 0; i < 4; ++i)
#pragma unroll
        for (int j = 0; j < 4; ++j) acc[i][j] = fmaf(ar[i], br[j], acc[i][j]);
    }
    __syncthreads();
  }
  const int n0 = bn + (tx << 2);
  float4 bsv = *(const float4*)(bias + n0);
#pragma unroll
  for (int i = 0; i < 4; ++i) {
    int m = bm + (ty << 2) + i;
    float4 res;
    res.x = acc[i][0] + bsv.x; res.y = acc[i][1] + bsv.y;
    res.z = acc[i][2] + bsv.z; res.w = acc[i][3] + bsv.w;
    if (add) {
      float4 ad = *(const float4*)(add + (size_t)m * N + n0);
      res.x += ad.x; res.y += ad.y; res.z += ad.z; res.w += ad.w;
    }
    *(float4*)(C + (size_t)m * N + n0) = res;
  }
}

// ---------- fused 2-layer persistent GRU scan, dataflow-synced ----------
// 64 WGs x 256 threads, no barriers, no fences. WG owns rows [wg*8, wg*8+8).
// h values travel as 64-bit {value,tag} pairs via relaxed agent atomics.
// ring0 slot[t&1] holds h0[t] tagged t+1; ring1 slot[(t+1)&1] holds h1[t-?]...
// Tick t: poll h0[t-1] (tag t) + h1[t-2] (tag t-1); compute h0[t], h1[t-1]; store.
// Re-poll is straggler-only: after the first full sweep, each lane re-loads
// only the pairs whose tag hasn't arrived (exec-masked) — keeps retry traffic
// to a few cache lines chip-wide instead of MBs per sweep.
// Slot-reuse safety: stores are data+control-dependent on completed polls
// (wave-wide ballot couples both halves), so a producer reaching tick t+1
// transitively proves every WG finished the reads of the slot it overwrites.
__global__ __launch_bounds__(256, 1) void k_gru_fused(
    const float* __restrict__ ih0,   // [T][1536] precomputed x@W_ih0^T + b_ih0
    const float* __restrict__ Whh0, const float* __restrict__ bhh0,
    const float* __restrict__ Wih1, const float* __restrict__ bih1,
    const float* __restrict__ Whh1, const float* __restrict__ bhh1,
    float* __restrict__ h1seq,       // [T][512]
    ull* ring0,                      // [2][512] pairs, zeroed each launch
    ull* ring1) {                    // [2][512] pairs, zeroed each launch
  const int wg = blockIdx.x, tid = threadIdx.x;
  const int l32 = tid & 31, jl = tid >> 5;   // jl 0..7
  const int r = (wg << 3) + jl;              // global row 0..511
  const bool isH1 = (tid & 32) != 0;         // upper half-wave polls ring1
  // weight slices in registers: elements l32*4 + q*128 + k of row r
  float w0f[3][16], w1if[3][16], w1hf[3][16];
#pragma unroll
  for (int g = 0; g < 3; ++g)
#pragma unroll
    for (int q = 0; q < 4; ++q) {
      size_t off = ((size_t)g << 18) + ((size_t)r << 9) + (l32 << 2) + (q << 7);
      float4 v0 = *(const float4*)(Whh0 + off);
      float4 v1 = *(const float4*)(Wih1 + off);
      float4 v2 = *(const float4*)(Whh1 + off);
      w0f[g][q * 4 + 0] = v0.x; w0f[g][q * 4 + 1] = v0.y; w0f[g][q * 4 + 2] = v0.z; w0f[g][q * 4 + 3] = v0.w;
      w1if[g][q * 4 + 0] = v1.x; w1if[g][q * 4 + 1] = v1.y; w1if[g][q * 4 + 2] = v1.z; w1if[g][q * 4 + 3] = v1.w;
      w1hf[g][q * 4 + 0] = v2.x; w1hf[g][q * 4 + 1] = v2.y; w1hf[g][q * 4 + 2] = v2.z; w1hf[g][q * 4 + 3] = v2.w;
    }
  float bh00 = 0, bh01 = 0, bh02 = 0, bi10 = 0, bi11 = 0, bi12 = 0,
        bh10 = 0, bh11 = 0, bh12 = 0;
  if (l32 == 0) {
    bh00 = bhh0[r]; bh01 = bhh0[512 + r]; bh02 = bhh0[1024 + r];
    bi10 = bih1[r]; bi11 = bih1[512 + r]; bi12 = bih1[1024 + r];
    bh10 = bhh1[r]; bh11 = bhh1[512 + r]; bh12 = bhh1[1024 + r];
  }
  float h0own = 0.f, h1own = 0.f;  // valid in l32==0 lanes
  for (int t = 0; t <= T_STEPS; ++t) {
    // prefetch ih0 row (independent of ring data) — loads in flight before poll
    float i0 = 0, i1 = 0, i2 = 0;
    if (l32 == 0 && t < T_STEPS) {
      const float* ihp = ih0 + (size_t)t * 1536 + r;
      i0 = ihp[0]; i1 = ihp[512]; i2 = ihp[1024];
    }
    // poll my half's ring slot until all 16 pairs carry the expected tag;
    // re-load ONLY stale pairs after the first sweep
    const unsigned exp0 = (unsigned)t;
    const unsigned exp1 = (t > 0) ? (unsigned)(t - 1) : 0u;
    ull* sp = isH1 ? (ring1 + ((t & 1) << 9)) : (ring0 + (((t + 1) & 1) << 9));
    const unsigned expm = isH1 ? exp1 : exp0;
    ull P[16];
    bool need[16];
#pragma unroll
    for (int i = 0; i < 16; ++i) need[i] = true;
    while (true) {
      unsigned anybad = 0;
#pragma unroll
      for (int q = 0; q < 4; ++q)
#pragma unroll
        for (int k = 0; k < 4; ++k) {
          const int i = q * 4 + k;
          if (need[i]) {
            P[i] = __hip_atomic_load(sp + (l32 << 2) + (q << 7) + k,
                                     __ATOMIC_RELAXED, __HIP_MEMORY_SCOPE_AGENT);
            need[i] = (((unsigned)P[i]) != expm);
          }
          anybad |= (unsigned)need[i];
        }
      if (__ballot(anybad != 0) == 0ull) break;
    }
    __asm__ volatile("" ::: "memory");
    // decode + cross-half exchange: every lane gets both h0 and h1 slices
    float hv0v[16], hv1v[16];
#pragma unroll
    for (int i = 0; i < 16; ++i) {
      float mine = __uint_as_float((unsigned)(P[i] >> 32));
      float other = __shfl_xor(mine, 32);
      hv0v[i] = isH1 ? other : mine;
      hv1v[i] = isH1 ? mine : other;
    }
    float a0 = 0, a1 = 0, a2 = 0;   // h0[t-1] . Whh0[row]
    float e0 = 0, e1 = 0, e2 = 0;   // h0[t-1] . Wih1[row]
    float d0 = 0, d1 = 0, d2 = 0;   // h1[t-2] . Whh1[row]
#pragma unroll
    for (int i = 0; i < 16; ++i) {
      float h = hv0v[i], g = hv1v[i];
      a0 = fmaf(h, w0f[0][i], a0); a1 = fmaf(h, w0f[1][i], a1); a2 = fmaf(h, w0f[2][i], a2);
      e0 = fmaf(h, w1if[0][i], e0); e1 = fmaf(h, w1if[1][i], e1); e2 = fmaf(h, w1if[2][i], e2);
      d0 = fmaf(g, w1hf[0][i], d0); d1 = fmaf(g, w1hf[1][i], d1); d2 = fmaf(g, w1hf[2][i], d2);
    }
#pragma unroll
    for (int m = 16; m; m >>= 1) {
      a0 += __shfl_xor(a0, m); a1 += __shfl_xor(a1, m); a2 += __shfl_xor(a2, m);
      e0 += __shfl_xor(e0, m); e1 += __shfl_xor(e1, m); e2 += __shfl_xor(e2, m);
      d0 += __shfl_xor(d0, m); d1 += __shfl_xor(d1, m); d2 += __shfl_xor(d2, m);
    }
    if (l32 == 0) {
      if (t < T_STEPS) {
        float rr = sigmoidf_(i0 + a0 + bh00);
        float zz = sigmoidf_(i1 + a1 + bh01);
        float nn = tanhf(fmaf(rr, a2 + bh02, i2));
        h0own = fmaf(zz, h0own - nn, nn);
        __hip_atomic_store(ring0 + ((t & 1) << 9) + r, packpair(h0own, (unsigned)(t + 1)),
                           __ATOMIC_RELAXED, __HIP_MEMORY_SCOPE_AGENT);
      }
      if (t >= 1) {
        float rr = sigmoidf_(e0 + bi10 + d0 + bh10);
        float zz = sigmoidf_(e1 + bi11 + d1 + bh11);
        float nn = tanhf(fmaf(rr, d2 + bh12, e2 + bi12));
        h1own = fmaf(zz, h1own - nn, nn);
        __hip_atomic_store(ring1 + (((t + 1) & 1) << 9) + r, packpair(h1own, (unsigned)t),
                           __ATOMIC_RELAXED, __HIP_MEMORY_SCOPE_AGENT);
        h1seq[(size_t)(t - 1) * 512 + r] = h1own;
      }
    }
  }
}

// ---------- alpha = sigmoid(c . w + b), one wave per row ----------
__global__ __launch_bounds__(256) void k_alpha(const float* __restrict__ c,
                                               const float* __restrict__ w,
                                               const float* __restrict__ b,
                                               float* __restrict__ alpha) {
  const int wave = threadIdx.x >> 6, lane = threadIdx.x & 63;
  const int t = (blockIdx.x << 2) + wave;
  const float* cr = c + (size_t)t * 512;
  float acc = 0.f;
#pragma unroll
  for (int q = 0; q < 8; ++q) acc = fmaf(cr[lane + (q << 6)], w[lane + (q << 6)], acc);
#pragma unroll
  for (int m = 32; m; m >>= 1) acc += __shfl_xor(acc, m);
  if (lane == 0) alpha[t] = sigmoidf_(acc + b[0]);
}

// ---------- df_out grouped linear + tanh + conv(KT=2) add, one block per row ----------
__global__ __launch_bounds__(256) void k_dfout_conv(const float* __restrict__ c,
                                                    const float* __restrict__ Wd,
                                                    const float* __restrict__ c0,
                                                    const float* __restrict__ wc,
                                                    const float* __restrict__ bc,
                                                    float* __restrict__ out) {
  __shared__ float cs[512];
  __shared__ float A0[64 * 96];
  __shared__ float A1[64 * 96];
  __shared__ float wcs[1280];
  __shared__ float cc[960];
  const int t = blockIdx.x, tid = threadIdx.x;
  ((float2*)cs)[tid] = ((const float2*)(c + (size_t)t * 512))[tid];
  for (int idx = tid; idx < 64 * 96; idx += 256) {
    int ci = idx / 96, f = idx - ci * 96;
    size_t base = (size_t)ci * ((size_t)T_STEPS * 96) + (size_t)t * 96 + f;
    A1[idx] = c0[base];
    A0[idx] = (t == 0) ? 0.f : c0[base - 96];
  }
  for (int idx = tid; idx < 1280; idx += 256) wcs[idx] = wc[idx];
  __syncthreads();
  for (int idx = tid; idx < 960; idx += 256) {
    int f = idx / 10, co = idx - f * 10;
    float acc = bc[co];
    const float* w = wcs + (co << 7);  // (co, ci, kt)
#pragma unroll 16
    for (int ci = 0; ci < 64; ++ci) {
      acc = fmaf(A0[ci * 96 + f], w[ci * 2 + 0], acc);
      acc = fmaf(A1[ci * 96 + f], w[ci * 2 + 1], acc);
    }
    cc[idx] = acc;
  }
  __syncthreads();
  for (int idx = tid; idx < 960; idx += 256) {
    int g = idx / 120, o = idx - g * 120;
    const float* wp = Wd + g * 7680 + o;  // Wd[g][i][o], stride 120 over i
    const float* ep = cs + (g << 6);
    float acc = 0.f;
#pragma unroll 16
    for (int i = 0; i < 64; ++i) acc = fmaf(ep[i], wp[i * 120], acc);
    out[(size_t)t * 960 + idx] = tanhf(acc) + cc[idx];
  }
}

extern "C" void kernel_launch(void* const* d_in, const int* in_sizes, int n_in,
                              void* d_out, int out_size, void* d_ws, size_t ws_size,
                              hipStream_t stream) {
  const float* emb       = (const float*)d_in[0];
  const float* c0        = (const float*)d_in[1];
  const float* lin_in_w  = (const float*)d_in[2];
  const float* w_ih      = (const float*)d_in[3];  // (2,3,512,512)
  const float* w_hh      = (const float*)d_in[4];
  const float* b_ih      = (const float*)d_in[5];  // (2,3,512)
  const float* b_hh      = (const float*)d_in[6];
  const float* skip_w    = (const float*)d_in[7];
  const float* skip_b    = (const float*)d_in[8];
  const float* lin_out_w = (const float*)d_in[9];
  const float* df_skip_w = (const float*)d_in[10];
  const float* df_skip_b = (const float*)d_in[11];
  const float* fc_a_w    = (const float*)d_in[12];
  const float* fc_a_b    = (const float*)d_in[13];
  const float* df_out_w  = (const float*)d_in[14];
  const float* convp_w   = (const float*)d_in[15];
  const float* convp_b   = (const float*)d_in[16];

  const size_t T = T_STEPS;
  float* x    = (float*)d_ws;             // T*512
  float* ih   = x + T * 512;              // T*1536
  float* h1   = ih + T * 1536;            // T*512
  ull* ring0  = (ull*)(h1 + T * 512);     // 2*512 pairs
  ull* ring1  = ring0 + 1024;             // 2*512 pairs
  float* sbuf = ih;                       // reuse ih region after scan
  float* vbuf = ih + T * 512;
  float* cbuf = ih + 2 * T * 512;
  float* outc = (float*)d_out;
  float* outa = outc + T * 960;

  // x = relu(grouped_linear(emb, lin_in_w))
  k_grouped_relu<<<T_STEPS, 256, 0, stream>>>(emb, lin_in_w, x);
  // ih0 = x @ W_ih0^T + b_ih0
  k_gemm_rr<<<dim3(128, 24), 256, 0, stream>>>(x, w_ih, b_ih, nullptr, ih, 1536);
  // fused pipelined 2-layer scan (dataflow sync, straggler-only re-poll)
  (void)hipMemsetAsync(ring0, 0, 2048 * sizeof(ull), stream);
  k_gru_fused<<<NWG2, 256, 0, stream>>>(ih, w_hh, b_hh,
                                        w_ih + 786432, b_ih + 1536,
                                        w_hh + 786432, b_hh + 1536,
                                        h1, ring0, ring1);
  // s = h1 + x @ skip_w^T + skip_b
  k_gemm_rr<<<dim3(128, 8), 256, 0, stream>>>(x, skip_w, skip_b, h1, sbuf, 512);
  // v = relu(grouped_linear(s, lin_out_w))
  k_grouped_relu<<<T_STEPS, 256, 0, stream>>>(sbuf, lin_out_w, vbuf);
  // c = v + emb @ df_skip_w^T + df_skip_b
  k_gemm_rr<<<dim3(128, 8), 256, 0, stream>>>(emb, df_skip_w, df_skip_b, vbuf, cbuf, 512);
  // alpha = sigmoid(c @ fc_a_w^T + fc_a_b)
  k_alpha<<<T_STEPS / 4, 256, 0, stream>>>(cbuf, fc_a_w, fc_a_b, outa);
  // out = tanh(grouped_linear(c, df_out_w)) + conv(c0)
  k_dfout_conv<<<T_STEPS, 256, 0, stream>>>(cbuf, df_out_w, c0, convp_w, convp_b, outc);
  (void)in_sizes; (void)n_in; (void)out_size; (void)ws_size;
}

// Round 6
// 31127.255 us; speedup vs baseline: 1.6681x; 1.6681x over previous
//
#include <hip/hip_runtime.h>
#include <hip/hip_bf16.h>
#include <cstdint>

#define T_STEPS 8192
#define NWG3 64

typedef unsigned long long ull;

__device__ __forceinline__ float sigmoidf_(float v) { return 1.f / (1.f + __expf(-v)); }

__device__ __forceinline__ ull packpair(float v, unsigned tag) {
  return ((ull)__float_as_uint(v) << 32) | (ull)tag;
}

__device__ __forceinline__ void acc4(float& acc, const float4& wv, const float4& hv) {
  acc = fmaf(hv.x, wv.x, acc); acc = fmaf(hv.y, wv.y, acc);
  acc = fmaf(hv.z, wv.z, acc); acc = fmaf(hv.w, wv.w, acc);
}

// ---------- grouped linear (8 groups of 64x64) + relu, one block per row ----------
__global__ __launch_bounds__(256) void k_grouped_relu(const float* __restrict__ in,
                                                      const float* __restrict__ W,
                                                      float* __restrict__ out) {
  __shared__ float es[512];
  const int t = blockIdx.x;
  const int tid = threadIdx.x;
  const float* inr = in + (size_t)t * 512;
  ((float2*)es)[tid] = ((const float2*)inr)[tid];
  __syncthreads();
#pragma unroll
  for (int rep = 0; rep < 2; ++rep) {
    int jj = tid + rep * 256;
    int g = jj >> 6, o = jj & 63;
    const float* wp = W + (g << 12) + o;   // W[g][i][o], stride 64 over i
    const float* ep = es + (g << 6);
    float acc = 0.f;
#pragma unroll 8
    for (int i = 0; i < 64; ++i) acc = fmaf(ep[i], wp[i << 6], acc);
    out[(size_t)t * 512 + jj] = fmaxf(acc, 0.f);
  }
}

// ---------- C[M,N] = A[M,512] * B[N,512]^T + bias[N] (+ add[M,N]) ----------
__global__ __launch_bounds__(256) void k_gemm_rr(const float* __restrict__ A,
                                                 const float* __restrict__ B,
                                                 const float* __restrict__ bias,
                                                 const float* __restrict__ add,
                                                 float* __restrict__ C, int N) {
  __shared__ float As[64][68];  // [k][m]
  __shared__ float Bs[64][68];  // [k][n]
  const int bm = blockIdx.x << 6, bn = blockIdx.y << 6;
  const int tid = threadIdx.x;
  const int tx = tid & 15, ty = tid >> 4;
  float acc[4][4] = {};
  for (int k0 = 0; k0 < 512; k0 += 64) {
#pragma unroll
    for (int u = 0; u < 4; ++u) {
      int f4 = (u << 8) + tid;          // 0..1023
      int m = f4 >> 4;                  // 0..63
      int kq = (f4 & 15) << 2;          // 0..60
      float4 av = *(const float4*)(A + (size_t)(bm + m) * 512 + k0 + kq);
      As[kq + 0][m] = av.x; As[kq + 1][m] = av.y; As[kq + 2][m] = av.z; As[kq + 3][m] = av.w;
      float4 bv = *(const float4*)(B + (size_t)(bn + m) * 512 + k0 + kq);
      Bs[kq + 0][m] = bv.x; Bs[kq + 1][m] = bv.y; Bs[kq + 2][m] = bv.z; Bs[kq + 3][m] = bv.w;
    }
    __syncthreads();
#pragma unroll
    for (int k = 0; k < 64; ++k) {
      float4 a4 = *(const float4*)(&As[k][ty << 2]);
      float4 b4 = *(const float4*)(&Bs[k][tx << 2]);
      float ar[4] = {a4.x, a4.y, a4.z, a4.w};
      float br[4] = {b4.x, b4.y, b4.z, b4.w};
#pragma unroll
      for (int i = 0; i < 4; ++i)
#pragma unroll
        for (int j = 0; j < 4; ++j) acc[i][j] = fmaf(ar[i], br[j], acc[i][j]);
    }
    __syncthreads();
  }
  const int n0 = bn + (tx << 2);
  float4 bsv = *(const float4*)(bias + n0);
#pragma unroll
  for (int i = 0; i < 4; ++i) {
    int m = bm + (ty << 2) + i;
    float4 res;
    res.x = acc[i][0] + bsv.x; res.y = acc[i][1] + bsv.y;
    res.z = acc[i][2] + bsv.z; res.w = acc[i][3] + bsv.w;
    if (add) {
      float4 ad = *(const float4*)(add + (size_t)m * N + n0);
      res.x += ad.x; res.y += ad.y; res.z += ad.z; res.w += ad.w;
    }
    *(float4*)(C + (size_t)m * N + n0) = res;
  }
}

// ---------- fused 2-layer persistent GRU scan, tagged-pair dataflow v2 ----------
// 64 WGs x 512 threads (8 waves). Wave w owns global row r = wg*8+w of BOTH
// layers; its 64 lanes hold 8-float weight slices of the 9 gate-rows
// (Whh0 x3, Wih1 x3, Whh1 x3) in registers (18 float4/thread).
// Sync: h values are 64-bit {value,tag} pairs in MALL (relaxed agent atomics).
// Polling is minimal: waves 0-3 poll h0's 512 pairs (2 pairs/lane), waves 4-7
// poll h1's; on tag-match the wave deposits decoded floats in LDS, barrier,
// everyone reads slices from LDS. 2 atomic loads/lane/sweep total.
// Tick t: needs h0[t-1] (ring0 slot (t+1)&1, tag t) and h1[t-2] (ring1 slot
// t&1, tag max(t-1,0)); computes h0[t] (store slot t&1, tag t+1) and h1[t-1]
// (store slot (t+1)&1, tag t). Rings memset to 0 each launch = valid initial
// state (h=-0 values, tag 0). Slot-reuse safety: a WG's ring store certifies
// its own completed reads (store is after barrier after LDS-read after poll),
// and reaching tick t+1 requires ALL WGs' tick-t stores -> transitively every
// WG finished reading the slot being overwritten.
__global__ __launch_bounds__(512, 1) void k_gru_fused(
    const float* __restrict__ ih0,   // [T][1536] precomputed x@W_ih0^T + b_ih0
    const float* __restrict__ Whh0, const float* __restrict__ bhh0,
    const float* __restrict__ Wih1, const float* __restrict__ bih1,
    const float* __restrict__ Whh1, const float* __restrict__ bhh1,
    float* __restrict__ h1seq,       // [T][512]
    ull* ring0,                      // [2][512] pairs, zeroed each launch
    ull* ring1) {                    // [2][512] pairs, zeroed each launch
  __shared__ float h0s[512];
  __shared__ float h1s[512];
  const int wg = blockIdx.x, tid = threadIdx.x;
  const int w = tid >> 6, l = tid & 63;
  const int r = (wg << 3) + w;              // this wave's row (0..511)
  const bool pollH1 = (w >= 4);
  const int pidx = ((w & 3) << 6) + l;      // 0..255; polls pairs pidx, pidx+256

  // register-resident weights: 9 gate-rows x lane slice [l*8, l*8+8)
  float4 W9[9][2];
#pragma unroll
  for (int g = 0; g < 3; ++g) {
    size_t off = ((size_t)g << 18) + ((size_t)r << 9) + ((size_t)l << 3);
    W9[g][0]     = *(const float4*)(Whh0 + off); W9[g][1]     = *(const float4*)(Whh0 + off + 4);
    W9[3 + g][0] = *(const float4*)(Wih1 + off); W9[3 + g][1] = *(const float4*)(Wih1 + off + 4);
    W9[6 + g][0] = *(const float4*)(Whh1 + off); W9[6 + g][1] = *(const float4*)(Whh1 + off + 4);
  }
  float b9[9] = {};
  if (l == 0) {
#pragma unroll
    for (int g = 0; g < 3; ++g) {
      b9[g] = bhh0[(g << 9) + r];
      b9[3 + g] = bih1[(g << 9) + r];
      b9[6 + g] = bhh1[(g << 9) + r];
    }
  }
  float h0own = 0.f, h1own = 0.f;  // lane 0 only

  for (int t = 0; t <= T_STEPS; ++t) {
    // ih0 prefetch: in flight during the poll
    float i0 = 0.f, i1 = 0.f, i2 = 0.f;
    if (l == 0 && t < T_STEPS) {
      const float* p = ih0 + (size_t)t * 1536 + r;
      i0 = p[0]; i1 = p[512]; i2 = p[1024];
    }
    // --- poll my 2 pairs ---
    {
      ull* sp = pollH1 ? (ring1 + ((t & 1) << 9)) : (ring0 + (((t + 1) & 1) << 9));
      const unsigned expm = pollH1 ? (unsigned)((t > 0) ? t - 1 : 0) : (unsigned)t;
      ull Pa, Pb;
      for (;;) {
        Pa = __hip_atomic_load(sp + pidx, __ATOMIC_RELAXED, __HIP_MEMORY_SCOPE_AGENT);
        Pb = __hip_atomic_load(sp + pidx + 256, __ATOMIC_RELAXED, __HIP_MEMORY_SCOPE_AGENT);
        bool bad = (((unsigned)Pa) != expm) | (((unsigned)Pb) != expm);
        if (__ballot(bad) == 0ull) break;
      }
      float* dst = pollH1 ? h1s : h0s;
      dst[pidx] = __uint_as_float((unsigned)(Pa >> 32));
      dst[pidx + 256] = __uint_as_float((unsigned)(Pb >> 32));
    }
    __syncthreads();
    // --- read my h slices from LDS into registers ---
    float4 h0a = *(const float4*)(h0s + (l << 3));
    float4 h0b = *(const float4*)(h0s + (l << 3) + 4);
    float4 h1a = *(const float4*)(h1s + (l << 3));
    float4 h1b = *(const float4*)(h1s + (l << 3) + 4);
    __syncthreads();  // LDS free for next tick's poll deposits
    // --- 9 dot products + wave reduce ---
    float acc[9];
#pragma unroll
    for (int i = 0; i < 9; ++i) acc[i] = 0.f;
#pragma unroll
    for (int i = 0; i < 6; ++i) { acc4(acc[i], W9[i][0], h0a); acc4(acc[i], W9[i][1], h0b); }
#pragma unroll
    for (int i = 6; i < 9; ++i) { acc4(acc[i], W9[i][0], h1a); acc4(acc[i], W9[i][1], h1b); }
#pragma unroll
    for (int m = 1; m < 64; m <<= 1)
#pragma unroll
      for (int i = 0; i < 9; ++i) acc[i] += __shfl_xor(acc[i], m);
    // --- lane 0: activations, ring stores, output ---
    if (l == 0) {
      if (t < T_STEPS) {
        float rr = sigmoidf_(i0 + acc[0] + b9[0]);
        float zz = sigmoidf_(i1 + acc[1] + b9[1]);
        float nn = tanhf(fmaf(rr, acc[2] + b9[2], i2));
        h0own = fmaf(zz, h0own - nn, nn);
        __hip_atomic_store(ring0 + ((t & 1) << 9) + r, packpair(h0own, (unsigned)(t + 1)),
                           __ATOMIC_RELAXED, __HIP_MEMORY_SCOPE_AGENT);
      }
      if (t >= 1) {
        float rr = sigmoidf_(acc[3] + b9[3] + acc[6] + b9[6]);
        float zz = sigmoidf_(acc[4] + b9[4] + acc[7] + b9[7]);
        float nn = tanhf(fmaf(rr, acc[8] + b9[8], acc[5] + b9[5]));
        h1own = fmaf(zz, h1own - nn, nn);
        __hip_atomic_store(ring1 + (((t + 1) & 1) << 9) + r, packpair(h1own, (unsigned)t),
                           __ATOMIC_RELAXED, __HIP_MEMORY_SCOPE_AGENT);
        h1seq[(size_t)(t - 1) * 512 + r] = h1own;
      }
    }
  }
}

// ---------- alpha = sigmoid(c . w + b), one wave per row ----------
__global__ __launch_bounds__(256) void k_alpha(const float* __restrict__ c,
                                               const float* __restrict__ w,
                                               const float* __restrict__ b,
                                               float* __restrict__ alpha) {
  const int wave = threadIdx.x >> 6, lane = threadIdx.x & 63;
  const int t = (blockIdx.x << 2) + wave;
  const float* cr = c + (size_t)t * 512;
  float acc = 0.f;
#pragma unroll
  for (int q = 0; q < 8; ++q) acc = fmaf(cr[lane + (q << 6)], w[lane + (q << 6)], acc);
#pragma unroll
  for (int m = 32; m; m >>= 1) acc += __shfl_xor(acc, m);
  if (lane == 0) alpha[t] = sigmoidf_(acc + b[0]);
}

// ---------- df_out grouped linear + tanh + conv(KT=2) add, one block per row ----------
__global__ __launch_bounds__(256) void k_dfout_conv(const float* __restrict__ c,
                                                    const float* __restrict__ Wd,
                                                    const float* __restrict__ c0,
                                                    const float* __restrict__ wc,
                                                    const float* __restrict__ bc,
                                                    float* __restrict__ out) {
  __shared__ float cs[512];
  __shared__ float A0[64 * 96];
  __shared__ float A1[64 * 96];
  __shared__ float wcs[1280];
  __shared__ float cc[960];
  const int t = blockIdx.x, tid = threadIdx.x;
  ((float2*)cs)[tid] = ((const float2*)(c + (size_t)t * 512))[tid];
  for (int idx = tid; idx < 64 * 96; idx += 256) {
    int ci = idx / 96, f = idx - ci * 96;
    size_t base = (size_t)ci * ((size_t)T_STEPS * 96) + (size_t)t * 96 + f;
    A1[idx] = c0[base];
    A0[idx] = (t == 0) ? 0.f : c0[base - 96];
  }
  for (int idx = tid; idx < 1280; idx += 256) wcs[idx] = wc[idx];
  __syncthreads();
  for (int idx = tid; idx < 960; idx += 256) {
    int f = idx / 10, co = idx - f * 10;
    float acc = bc[co];
    const float* w = wcs + (co << 7);  // (co, ci, kt)
#pragma unroll 16
    for (int ci = 0; ci < 64; ++ci) {
      acc = fmaf(A0[ci * 96 + f], w[ci * 2 + 0], acc);
      acc = fmaf(A1[ci * 96 + f], w[ci * 2 + 1], acc);
    }
    cc[idx] = acc;
  }
  __syncthreads();
  for (int idx = tid; idx < 960; idx += 256) {
    int g = idx / 120, o = idx - g * 120;
    const float* wp = Wd + g * 7680 + o;  // Wd[g][i][o], stride 120 over i
    const float* ep = cs + (g << 6);
    float acc = 0.f;
#pragma unroll 16
    for (int i = 0; i < 64; ++i) acc = fmaf(ep[i], wp[i * 120], acc);
    out[(size_t)t * 960 + idx] = tanhf(acc) + cc[idx];
  }
}

extern "C" void kernel_launch(void* const* d_in, const int* in_sizes, int n_in,
                              void* d_out, int out_size, void* d_ws, size_t ws_size,
                              hipStream_t stream) {
  const float* emb       = (const float*)d_in[0];
  const float* c0        = (const float*)d_in[1];
  const float* lin_in_w  = (const float*)d_in[2];
  const float* w_ih      = (const float*)d_in[3];  // (2,3,512,512)
  const float* w_hh      = (const float*)d_in[4];
  const float* b_ih      = (const float*)d_in[5];  // (2,3,512)
  const float* b_hh      = (const float*)d_in[6];
  const float* skip_w    = (const float*)d_in[7];
  const float* skip_b    = (const float*)d_in[8];
  const float* lin_out_w = (const float*)d_in[9];
  const float* df_skip_w = (const float*)d_in[10];
  const float* df_skip_b = (const float*)d_in[11];
  const float* fc_a_w    = (const float*)d_in[12];
  const float* fc_a_b    = (const float*)d_in[13];
  const float* df_out_w  = (const float*)d_in[14];
  const float* convp_w   = (const float*)d_in[15];
  const float* convp_b   = (const float*)d_in[16];

  const size_t T = T_STEPS;
  float* x    = (float*)d_ws;             // T*512
  float* ih   = x + T * 512;              // T*1536
  float* h1   = ih + T * 1536;            // T*512
  ull* ring0  = (ull*)(h1 + T * 512);     // 2*512 pairs
  ull* ring1  = ring0 + 1024;             // 2*512 pairs
  float* sbuf = ih;                       // reuse ih region after scan
  float* vbuf = ih + T * 512;
  float* cbuf = ih + 2 * T * 512;
  float* outc = (float*)d_out;
  float* outa = outc + T * 960;

  // x = relu(grouped_linear(emb, lin_in_w))
  k_grouped_relu<<<T_STEPS, 256, 0, stream>>>(emb, lin_in_w, x);
  // ih0 = x @ W_ih0^T + b_ih0
  k_gemm_rr<<<dim3(128, 24), 256, 0, stream>>>(x, w_ih, b_ih, nullptr, ih, 1536);
  // fused pipelined 2-layer scan (tagged-pair dataflow, wave-per-row)
  (void)hipMemsetAsync(ring0, 0, 2048 * sizeof(ull), stream);
  k_gru_fused<<<NWG3, 512, 0, stream>>>(ih, w_hh, b_hh,
                                        w_ih + 786432, b_ih + 1536,
                                        w_hh + 786432, b_hh + 1536,
                                        h1, ring0, ring1);
  // s = h1 + x @ skip_w^T + skip_b
  k_gemm_rr<<<dim3(128, 8), 256, 0, stream>>>(x, skip_w, skip_b, h1, sbuf, 512);
  // v = relu(grouped_linear(s, lin_out_w))
  k_grouped_relu<<<T_STEPS, 256, 0, stream>>>(sbuf, lin_out_w, vbuf);
  // c = v + emb @ df_skip_w^T + df_skip_b
  k_gemm_rr<<<dim3(128, 8), 256, 0, stream>>>(emb, df_skip_w, df_skip_b, vbuf, cbuf, 512);
  // alpha = sigmoid(c @ fc_a_w^T + fc_a_b)
  k_alpha<<<T_STEPS / 4, 256, 0, stream>>>(cbuf, fc_a_w, fc_a_b, outa);
  // out = tanh(grouped_linear(c, df_out_w)) + conv(c0)
  k_dfout_conv<<<T_STEPS, 256, 0, stream>>>(cbuf, df_out_w, c0, convp_w, convp_b, outc);
  (void)in_sizes; (void)n_in; (void)out_size; (void)ws_size;
}